// Round 5
// baseline (1003.194 us; speedup 1.0000x reference)
//
#include <hip/hip_runtime.h>

// ProbSparse attention, round 5:
//  - proj_gemm_mfma: XOR-swizzled LDS (octet s = koct ^ ((row>>1)&3)) to kill
//    the 8-way ds_read_b128 bank conflicts (1.26e7 in R4).
//  - flash_attn: SPLIT 16->32 (2048 blocks, 2 chunks each); ctx_part/ml_part
//    live in d_out (dead between GEMMs and init_out); init_out moved after
//    combine_ctx.
//  - 3 weight splits batched into one launch (separate hi/lo per weight).
// B=4, L=S=4096, D_MODEL=1024, H=16, D_K=64, SAMPLE_K=N_TOP=40, SCALE=1/8.

#define NTOP 40
#define NSAMP 40
#define SCALE 0.125f
#define SPLIT 32
#define KEYS_PER_SPLIT 128   // 4096 / SPLIT
#define CHUNK 64
#define NCHUNK 2             // KEYS_PER_SPLIT / CHUNK

// workspace offsets (in floats)
#define Q_OFF    0ull
#define K_OFF    16777216ull
#define V_OFF    33554432ull
#define M_OFF    50331648ull   // 262144 floats
#define MTOP_OFF 50593792ull   // 2560 ints (reserve 4096)
#define WOT_OFF  50597888ull   // 1048576 floats
#define WHL_OFF  51646464ull   // 3x(1M+1M) shorts = 12 MB in old 16MB region
#define CTX_OFF  55971840ull   // 64*40*64 = 163840 floats
// d_out scratch (16777216 floats = 64 MB), dead between GEMMs and init_out:
//   ctxp: 32*64*64*64 = 8388608 floats, mlp: 32*64*64*2 = 262144 floats

typedef __attribute__((ext_vector_type(8))) short short8;
typedef __attribute__((ext_vector_type(4))) float floatx4;

// ---------------------------------------------------------------- bf16 split
__device__ inline unsigned short bf16_rne(float f) {
  unsigned u = __float_as_uint(f);
  unsigned r = (u + 0x7fffu + ((u >> 16) & 1u)) >> 16;
  return (unsigned short)r;
}

__device__ inline void split4(float4 v, ushort4& h, ushort4& l) {
  h.x = bf16_rne(v.x); l.x = bf16_rne(v.x - __uint_as_float((unsigned)h.x << 16));
  h.y = bf16_rne(v.y); l.y = bf16_rne(v.y - __uint_as_float((unsigned)h.y << 16));
  h.z = bf16_rne(v.z); l.z = bf16_rne(v.z - __uint_as_float((unsigned)h.z << 16));
  h.w = bf16_rne(v.w); l.w = bf16_rne(v.w - __uint_as_float((unsigned)h.w << 16));
}

__global__ __launch_bounds__(256) void split_bf16(
    const float* __restrict__ x, unsigned short* __restrict__ hi,
    unsigned short* __restrict__ lo, int n4) {
  int i = blockIdx.x * 256 + threadIdx.x;
  if (i >= n4) return;
  ushort4 h, l;
  split4(((const float4*)x)[i], h, l);
  ((ushort4*)hi)[i] = h;
  ((ushort4*)lo)[i] = l;
}

// one launch splits Wq/Wk/Wv into 3 distinct hi/lo pairs (1M shorts each)
__global__ __launch_bounds__(256) void splitW_bf16(
    const float* __restrict__ W0, const float* __restrict__ W1,
    const float* __restrict__ W2, unsigned short* __restrict__ hi,
    unsigned short* __restrict__ lo) {
  const int i = blockIdx.x * 256 + threadIdx.x;     // 0..262143 float4s
  const int s = blockIdx.y;                          // weight select
  const float* W = (s == 0) ? W0 : (s == 1) ? W1 : W2;
  ushort4 h, l;
  split4(((const float4*)W)[i], h, l);
  ((ushort4*)hi)[(size_t)s * 262144 + i] = h;
  ((ushort4*)lo)[(size_t)s * 262144 + i] = l;
}

// ---------------------------------------------------------------- async copy
__device__ inline void gl_lds16(const void* g, void* l) {
  __builtin_amdgcn_global_load_lds(
      (const __attribute__((address_space(1))) void*)g,
      (__attribute__((address_space(3))) void*)l, 16, 0, 0);
}

// ---------------------------------------------------------------- MFMA GEMM
// C[m][n] = sum_k X[m][k]*W[n][k] + bias[n]; M=16384, N=K=1024.
// 3 bf16 passes, fp32 MFMA accumulate. 128x128 tile, BK=32, 4 waves.
// LDS XOR swizzle: LDS (row, slot s) holds global octet g = s ^ ((row>>1)&3)
// -> fragment b128 reads hit each 4-bank group exactly 2x/quarter-wave (free).
__global__ __launch_bounds__(256) void proj_gemm_mfma(
    const unsigned short* __restrict__ Xh, const unsigned short* __restrict__ Xl,
    const unsigned short* __restrict__ Wh, const unsigned short* __restrict__ Wl,
    const float* __restrict__ bias, float* __restrict__ Out) {
  __shared__ unsigned short As[128 * 32];
  __shared__ unsigned short Bs[128 * 32];
  const int t = threadIdx.x;
  const int lane = t & 63;
  const int w = t >> 6;
  const int m0 = blockIdx.x * 128;
  const int n0 = blockIdx.y * 128;

  // staging: thread t fills LDS slot (row sr, octet-slot t&3); the global
  // octet that belongs there is (t&3) ^ ((sr>>1)&3). Same for row sr+64.
  const int sr = t >> 2;
  const int sc = (((t & 3) ^ ((sr >> 1) & 3))) * 8;
  char* AsB = (char*)As;
  char* BsB = (char*)Bs;
  const int ldsW = w * 1024;

  const int frow = lane & 15;
  const int koct = lane >> 4;
  const int koct2 = koct ^ ((frow >> 1) & 3);   // swizzled read slot
  const int m_off = (w & 1) * 64;
  const int n_off = (w >> 1) * 64;

  floatx4 acc[4][4] = {};

  const unsigned short* Asrc[3] = {Xh, Xl, Xh};
  const unsigned short* Bsrc[3] = {Wh, Wh, Wl};

  for (int pass = 0; pass < 3; ++pass) {
    const unsigned short* Ap = Asrc[pass];
    const unsigned short* Bp = Bsrc[pass];
    for (int k0 = 0; k0 < 1024; k0 += 32) {
      __syncthreads();
      gl_lds16(&Ap[(size_t)(m0 + sr) * 1024 + k0 + sc], AsB + ldsW);
      gl_lds16(&Ap[(size_t)(m0 + 64 + sr) * 1024 + k0 + sc], AsB + 4096 + ldsW);
      gl_lds16(&Bp[(size_t)(n0 + sr) * 1024 + k0 + sc], BsB + ldsW);
      gl_lds16(&Bp[(size_t)(n0 + 64 + sr) * 1024 + k0 + sc], BsB + 4096 + ldsW);
      __syncthreads();
      short8 af[4], bf[4];
#pragma unroll
      for (int mt = 0; mt < 4; ++mt)
        af[mt] = *(const short8*)(AsB + ((m_off + mt * 16 + frow) * 32 + koct2 * 8) * 2);
#pragma unroll
      for (int nt = 0; nt < 4; ++nt)
        bf[nt] = *(const short8*)(BsB + ((n_off + nt * 16 + frow) * 32 + koct2 * 8) * 2);
#pragma unroll
      for (int mt = 0; mt < 4; ++mt)
#pragma unroll
        for (int nt = 0; nt < 4; ++nt)
          acc[mt][nt] = __builtin_amdgcn_mfma_f32_16x16x32_bf16(
              af[mt], bf[nt], acc[mt][nt], 0, 0, 0);
    }
  }

#pragma unroll
  for (int nt = 0; nt < 4; ++nt) {
    const int n_g = n0 + n_off + nt * 16 + frow;
    const float bv = bias[n_g];
    const int h = n_g >> 6, d = n_g & 63;
#pragma unroll
    for (int mt = 0; mt < 4; ++mt) {
#pragma unroll
      for (int r = 0; r < 4; ++r) {
        const int m_g = m0 + m_off + mt * 16 + koct * 4 + r;
        const int b = m_g >> 12, l = m_g & 4095;
        Out[(((size_t)(b * 16 + h)) * 4096 + l) * 64 + d] = acc[mt][nt][r] + bv;
      }
    }
  }
}

// ---------------------------------------------------------------- transpose
__global__ __launch_bounds__(256) void transpose1024(
    const float* __restrict__ A, float* __restrict__ AT) {
  __shared__ float tile[64][68];
  const int t = threadIdx.x;
  const int x0 = blockIdx.x * 64;
  const int y0 = blockIdx.y * 64;
  const int tr = t >> 4;
  const int tc = (t & 15) * 4;
#pragma unroll
  for (int i = 0; i < 4; ++i) {
    int r = tr + i * 16;
    float4 v = *(const float4*)&A[(size_t)(y0 + r) * 1024 + x0 + tc];
    *(float4*)&tile[r][tc] = v;
  }
  __syncthreads();
#pragma unroll
  for (int i = 0; i < 4; ++i) {
    int r = tr + i * 16;
    float4 v;
    v.x = tile[tc + 0][r];
    v.y = tile[tc + 1][r];
    v.z = tile[tc + 2][r];
    v.w = tile[tc + 3][r];
    *(float4*)&AT[(size_t)(x0 + r) * 1024 + y0 + tc] = v;
  }
}

// ---------------------------------------------------------------- sample scores
__global__ __launch_bounds__(256) void sample_scores(
    const float* __restrict__ Q, const float* __restrict__ K,
    const int* __restrict__ samp, float* __restrict__ M) {
  __shared__ float Ks[NSAMP * 64];
  const int bh = blockIdx.y;
  const int t = threadIdx.x;
#pragma unroll
  for (int i = 0; i < 10; ++i) {
    int e = i * 256 + t;
    int s = e >> 6, d = e & 63;
    Ks[e] = K[((size_t)bh * 4096 + samp[s]) * 64 + d];
  }
  __syncthreads();
  const int l = blockIdx.x * 256 + t;
  const float* qp = &Q[((size_t)bh * 4096 + l) * 64];
  float4 q[16];
#pragma unroll
  for (int i = 0; i < 16; ++i) q[i] = *(const float4*)&qp[i * 4];
  float mx = -1e30f, sum = 0.f;
#pragma unroll
  for (int s = 0; s < NSAMP; ++s) {
    float acc = 0.f;
#pragma unroll
    for (int i = 0; i < 16; ++i) {
      float4 kv = *(const float4*)&Ks[s * 64 + i * 4];
      acc = fmaf(q[i].x, kv.x, acc);
      acc = fmaf(q[i].y, kv.y, acc);
      acc = fmaf(q[i].z, kv.z, acc);
      acc = fmaf(q[i].w, kv.w, acc);
    }
    mx = fmaxf(mx, acc);
    sum += acc;
  }
  M[(size_t)bh * 4096 + l] = mx - sum * (1.f / 40.f);
}

// ---------------------------------------------------------------- top-40
__global__ __launch_bounds__(256) void topk40(
    const float* __restrict__ M, int* __restrict__ Mtop) {
  __shared__ unsigned long long keys[4096];
  __shared__ unsigned long long red[256];
  const int bh = blockIdx.x;
  const int t = threadIdx.x;
#pragma unroll
  for (int i = 0; i < 16; ++i) {
    int idx = i * 256 + t;
    float f = M[(size_t)bh * 4096 + idx];
    unsigned int u = __float_as_uint(f);
    u = (u & 0x80000000u) ? ~u : (u | 0x80000000u);
    keys[idx] = (((unsigned long long)u) << 32) | (unsigned long long)(4095 - idx);
  }
  __syncthreads();
  for (int it = 0; it < NTOP; ++it) {
    unsigned long long best = 0;
#pragma unroll
    for (int i = 0; i < 16; ++i) {
      unsigned long long v = keys[i * 256 + t];
      best = v > best ? v : best;
    }
    red[t] = best;
    __syncthreads();
    for (int s = 128; s > 0; s >>= 1) {
      if (t < s) {
        unsigned long long o = red[t + s];
        if (o > red[t]) red[t] = o;
      }
      __syncthreads();
    }
    int idx = 4095 - (int)(red[0] & 0xFFFFFFFFull);
    if (t == 0) {
      Mtop[bh * NTOP + it] = idx;
      keys[idx] = 0;
    }
    __syncthreads();
  }
}

// ---------------------------------------------------------------- bias init
__global__ __launch_bounds__(256) void init_out(
    const float* __restrict__ bo, float* __restrict__ out) {
  const int t = threadIdx.x;
  const float4* bo4 = (const float4*)bo;
  float4* o4 = (float4*)out;
#pragma unroll
  for (int rep = 0; rep < 4; ++rep) {
    size_t idx = (size_t)rep * 1048576 + (size_t)blockIdx.x * 256 + t;
    o4[idx] = bo4[idx & 255];
  }
}

// ---------------------------------------------------------------- flash attention
// grid (SPLIT, 64), 256 threads (4 waves), 2 chunks of 64 keys per block.
__global__ __launch_bounds__(256) void flash_attn(
    const float* __restrict__ Q, const float* __restrict__ K,
    const float* __restrict__ V, const int* __restrict__ Mtop,
    float* __restrict__ ctx_part, float* __restrict__ ml_part) {
  __shared__ float Qs[NTOP * 64];   // 10.0 KB
  __shared__ float Ks[64 * 64];     // 16 KB, swizzled
  __shared__ float Vs[64 * 64];     // 16 KB, linear
  __shared__ float Sb[64 * 41];     // 10.25 KB
  __shared__ int topIdx[NTOP];
  const int t = threadIdx.x;
  const int lane = t & 63;
  const int w = t >> 6;
  const int split = blockIdx.x;
  const int bh = blockIdx.y;

  if (t < NTOP) topIdx[t] = Mtop[bh * NTOP + t];
  __syncthreads();
  for (int i = t; i < NTOP * 16; i += 256) {
    int r = i >> 4, c4 = i & 15;
    *(float4*)&Qs[r * 64 + c4 * 4] =
        *(const float4*)&Q[(((size_t)bh) * 4096 + topIdx[r]) * 64 + c4 * 4];
  }

  const float* Kb = K + (size_t)bh * 4096 * 64;
  const float* Vb = V + (size_t)bh * 4096 * 64;
  const int key0 = split * KEYS_PER_SPLIT;
  const int d0 = w * 16;
  const int s_in_row = lane & 15;
  const int lrow = lane >> 4;

  float m_r = -1e30f, l_r = 0.f;
  float4 acc0 = make_float4(0.f, 0.f, 0.f, 0.f);
  float4 acc1 = acc0, acc2 = acc0, acc3 = acc0;

  for (int c = 0; c < NCHUNK; ++c) {
    __syncthreads();
    const int jbase = key0 + c * CHUNK;
#pragma unroll
    for (int n = 0; n < 4; ++n) {
      const int slot0 = n * 256 + w * 64;
      const int j = (slot0 >> 4) + lrow;
      const int d4 = (s_in_row - j) & 15;
      gl_lds16(&Kb[(size_t)(jbase + j) * 64 + d4 * 4], (char*)Ks + slot0 * 16);
      gl_lds16(&Vb[(size_t)jbase * 64 + (size_t)(slot0 + lane) * 4],
               (char*)Vs + slot0 * 16);
    }
    __syncthreads();

    // ---- phase A: scores. lane = key, wave w covers rows [10w, 10w+10)
    float4 kr[16];
#pragma unroll
    for (int i = 0; i < 16; ++i)
      kr[i] = *(const float4*)&Ks[(lane * 16 + ((i + lane) & 15)) * 4];
#pragma unroll
    for (int rr = 0; rr < 10; ++rr) {
      const int r = w * 10 + rr;
      const float* qrow = &Qs[r * 64];
      float s = 0.f;
#pragma unroll
      for (int i = 0; i < 16; ++i) {
        float4 q4 = *(const float4*)&qrow[i * 4];
        s = fmaf(q4.x, kr[i].x, s);
        s = fmaf(q4.y, kr[i].y, s);
        s = fmaf(q4.z, kr[i].z, s);
        s = fmaf(q4.w, kr[i].w, s);
      }
      Sb[lane * 41 + r] = s * SCALE;
    }
    __syncthreads();

    // ---- phase B: lane = row (40 active), wave w owns d-slice [16w,16w+16)
    if (lane < NTOP) {
      float sv[64];
      float cm = -1e30f;
#pragma unroll
      for (int j2 = 0; j2 < 64; ++j2) {
        sv[j2] = Sb[j2 * 41 + lane];
        cm = fmaxf(cm, sv[j2]);
      }
      const float nm = fmaxf(m_r, cm);
      const float alpha = __expf(m_r - nm);
      m_r = nm;
      l_r *= alpha;
      acc0.x *= alpha; acc0.y *= alpha; acc0.z *= alpha; acc0.w *= alpha;
      acc1.x *= alpha; acc1.y *= alpha; acc1.z *= alpha; acc1.w *= alpha;
      acc2.x *= alpha; acc2.y *= alpha; acc2.z *= alpha; acc2.w *= alpha;
      acc3.x *= alpha; acc3.y *= alpha; acc3.z *= alpha; acc3.w *= alpha;
#pragma unroll
      for (int j2 = 0; j2 < 64; ++j2) {
        const float p = __expf(sv[j2] - nm);
        l_r += p;
        const float* vrow = &Vs[j2 * 64 + d0];
        float4 v0 = *(const float4*)&vrow[0];
        float4 v1 = *(const float4*)&vrow[4];
        float4 v2 = *(const float4*)&vrow[8];
        float4 v3 = *(const float4*)&vrow[12];
        acc0.x = fmaf(p, v0.x, acc0.x); acc0.y = fmaf(p, v0.y, acc0.y);
        acc0.z = fmaf(p, v0.z, acc0.z); acc0.w = fmaf(p, v0.w, acc0.w);
        acc1.x = fmaf(p, v1.x, acc1.x); acc1.y = fmaf(p, v1.y, acc1.y);
        acc1.z = fmaf(p, v1.z, acc1.z); acc1.w = fmaf(p, v1.w, acc1.w);
        acc2.x = fmaf(p, v2.x, acc2.x); acc2.y = fmaf(p, v2.y, acc2.y);
        acc2.z = fmaf(p, v2.z, acc2.z); acc2.w = fmaf(p, v2.w, acc2.w);
        acc3.x = fmaf(p, v3.x, acc3.x); acc3.y = fmaf(p, v3.y, acc3.y);
        acc3.z = fmaf(p, v3.z, acc3.z); acc3.w = fmaf(p, v3.w, acc3.w);
      }
    }
  }

  if (lane < NTOP) {
    size_t pbase = (((size_t)split * 64 + bh) * 64 + lane) * 64 + d0;
    *(float4*)&ctx_part[pbase + 0] = acc0;
    *(float4*)&ctx_part[pbase + 4] = acc1;
    *(float4*)&ctx_part[pbase + 8] = acc2;
    *(float4*)&ctx_part[pbase + 12] = acc3;
  }
  if (w == 0) {
    size_t mb = (((size_t)split * 64 + bh) * 64 + lane) * 2;
    ml_part[mb + 0] = m_r;
    ml_part[mb + 1] = l_r;
  }
}

// ---------------------------------------------------------------- combine splits
__global__ __launch_bounds__(256) void combine_ctx(
    const float* __restrict__ ctx_part, const float* __restrict__ ml_part,
    float* __restrict__ ctx) {
  const int bh = blockIdx.x;
  const int t = threadIdx.x;
  const int r = t & 63;
  const int dg = t >> 6;
  if (r >= NTOP) return;
  float mt = -1e30f;
#pragma unroll
  for (int s = 0; s < SPLIT; ++s)
    mt = fmaxf(mt, ml_part[(((size_t)s * 64 + bh) * 64 + r) * 2]);
  float Lt = 0.f;
  float4 a0 = make_float4(0.f, 0.f, 0.f, 0.f);
  float4 a1 = a0, a2 = a0, a3 = a0;
  const int d0 = dg * 16;
#pragma unroll
  for (int s = 0; s < SPLIT; ++s) {
    size_t mb = (((size_t)s * 64 + bh) * 64 + r) * 2;
    float ms = ml_part[mb], ls = ml_part[mb + 1];
    float wgt = __expf(ms - mt);
    Lt = fmaf(wgt, ls, Lt);
    size_t pb = (((size_t)s * 64 + bh) * 64 + r) * 64 + d0;
    float4 c0 = *(const float4*)&ctx_part[pb + 0];
    float4 c1 = *(const float4*)&ctx_part[pb + 4];
    float4 c2 = *(const float4*)&ctx_part[pb + 8];
    float4 c3 = *(const float4*)&ctx_part[pb + 12];
    a0.x = fmaf(wgt, c0.x, a0.x); a0.y = fmaf(wgt, c0.y, a0.y);
    a0.z = fmaf(wgt, c0.z, a0.z); a0.w = fmaf(wgt, c0.w, a0.w);
    a1.x = fmaf(wgt, c1.x, a1.x); a1.y = fmaf(wgt, c1.y, a1.y);
    a1.z = fmaf(wgt, c1.z, a1.z); a1.w = fmaf(wgt, c1.w, a1.w);
    a2.x = fmaf(wgt, c2.x, a2.x); a2.y = fmaf(wgt, c2.y, a2.y);
    a2.z = fmaf(wgt, c2.z, a2.z); a2.w = fmaf(wgt, c2.w, a2.w);
    a3.x = fmaf(wgt, c3.x, a3.x); a3.y = fmaf(wgt, c3.y, a3.y);
    a3.z = fmaf(wgt, c3.z, a3.z); a3.w = fmaf(wgt, c3.w, a3.w);
  }
  float inv = 1.f / Lt;
  size_t ob = ((size_t)bh * NTOP + r) * 64 + d0;
  a0.x *= inv; a0.y *= inv; a0.z *= inv; a0.w *= inv;
  a1.x *= inv; a1.y *= inv; a1.z *= inv; a1.w *= inv;
  a2.x *= inv; a2.y *= inv; a2.z *= inv; a2.w *= inv;
  a3.x *= inv; a3.y *= inv; a3.z *= inv; a3.w *= inv;
  *(float4*)&ctx[ob + 0] = a0;
  *(float4*)&ctx[ob + 4] = a1;
  *(float4*)&ctx[ob + 8] = a2;
  *(float4*)&ctx[ob + 12] = a3;
}

// ---------------------------------------------------------------- sparse out proj
__global__ __launch_bounds__(256) void scatter_out(
    const float* __restrict__ ctx, const int* __restrict__ Mtop,
    const float* __restrict__ WoT, float* __restrict__ out) {
  const int bx = blockIdx.x;
  const int bh = bx / NTOP;
  const int r = bx % NTOP;
  const int b = bh >> 4, h = bh & 15;
  const int t = threadIdx.x;
  __shared__ float crow[64];
  if (t < 16)
    *(float4*)&crow[t * 4] =
        *(const float4*)&ctx[((size_t)bh * NTOP + r) * 64 + t * 4];
  const int l = Mtop[bh * NTOP + r];
  __syncthreads();
  const int n0 = t * 4;
  float4 a = make_float4(0.f, 0.f, 0.f, 0.f);
#pragma unroll
  for (int d = 0; d < 64; ++d) {
    float cv = crow[d];
    float4 wv = *(const float4*)&WoT[(size_t)(h * 64 + d) * 1024 + n0];
    a.x = fmaf(cv, wv.x, a.x);
    a.y = fmaf(cv, wv.y, a.y);
    a.z = fmaf(cv, wv.z, a.z);
    a.w = fmaf(cv, wv.w, a.w);
  }
  float* orow = out + ((size_t)b * 4096 + l) * 1024 + n0;
  atomicAdd(&orow[0], a.x);
  atomicAdd(&orow[1], a.y);
  atomicAdd(&orow[2], a.z);
  atomicAdd(&orow[3], a.w);
}

// ---------------------------------------------------------------- launch
extern "C" void kernel_launch(void* const* d_in, const int* in_sizes, int n_in,
                              void* d_out, int out_size, void* d_ws, size_t ws_size,
                              hipStream_t stream) {
  const float* queries = (const float*)d_in[0];
  const float* keys    = (const float*)d_in[1];
  const float* values  = (const float*)d_in[2];
  const float* Wq = (const float*)d_in[3];
  const float* bq = (const float*)d_in[4];
  const float* Wk = (const float*)d_in[5];
  const float* bk = (const float*)d_in[6];
  const float* Wv = (const float*)d_in[7];
  const float* bv = (const float*)d_in[8];
  const float* Wo = (const float*)d_in[9];
  const float* bo = (const float*)d_in[10];
  const int* samp = (const int*)d_in[11];
  float* out = (float*)d_out;
  float* ws = (float*)d_ws;

  float* Qw   = ws + Q_OFF;
  float* Kw   = ws + K_OFF;
  float* Vw   = ws + V_OFF;
  float* Mws  = ws + M_OFF;
  int*   Mtop = (int*)(ws + MTOP_OFF);
  float* WoT  = ws + WOT_OFF;
  float* ctxf = ws + CTX_OFF;

  // weight hi/lo: 3 pairs in the WHL region (12 MB of the old 16 MB slot)
  unsigned short* Whi = (unsigned short*)(ws + WHL_OFF);
  unsigned short* Wlo = Whi + 3 * 1048576;

  // activation hi/lo in d_out (64 MB) until flash_attn needs it;
  // ctx_part/ml_part also in d_out (after GEMMs, before init_out).
  unsigned short* Xh = (unsigned short*)d_out;
  unsigned short* Xl = Xh + 16777216;
  float* ctxp = (float*)d_out;                 // 8388608 floats
  float* mlp  = (float*)d_out + 8388608;       // 262144 floats

  dim3 ggrid(128, 8);

  splitW_bf16<<<dim3(1024, 3), 256, 0, stream>>>(Wq, Wk, Wv, Whi, Wlo);

  split_bf16<<<16384, 256, 0, stream>>>(queries, Xh, Xl, 4194304);
  proj_gemm_mfma<<<ggrid, 256, 0, stream>>>(Xh, Xl, Whi, Wlo, bq, Qw);

  split_bf16<<<16384, 256, 0, stream>>>(keys, Xh, Xl, 4194304);
  proj_gemm_mfma<<<ggrid, 256, 0, stream>>>(Xh, Xl, Whi + 1048576,
                                            Wlo + 1048576, bk, Kw);

  split_bf16<<<16384, 256, 0, stream>>>(values, Xh, Xl, 4194304);
  proj_gemm_mfma<<<ggrid, 256, 0, stream>>>(Xh, Xl, Whi + 2097152,
                                            Wlo + 2097152, bv, Vw);

  transpose1024<<<dim3(16, 16), 256, 0, stream>>>(Wo, WoT);
  sample_scores<<<dim3(16, 64), 256, 0, stream>>>(Qw, Kw, samp, Mws);
  topk40<<<64, 256, 0, stream>>>(Mws, Mtop);
  flash_attn<<<dim3(SPLIT, 64), 256, 0, stream>>>(Qw, Kw, Vw, Mtop, ctxp, mlp);
  combine_ctx<<<64, 256, 0, stream>>>(ctxp, mlp, ctxf);
  init_out<<<4096, 256, 0, stream>>>(bo, out);
  scatter_out<<<2560, 256, 0, stream>>>(ctxf, Mtop, WoT, out);
}